// Round 5
// baseline (60352.539 us; speedup 1.0000x reference)
//
#include <hip/hip_runtime.h>

#define SS 2048
#define VV 29
#define HH 128
#define ROWS 16
#define NBLK 32     // 512 rows / 16 per block

typedef _Float16 h8 __attribute__((ext_vector_type(8)));
typedef float    f4 __attribute__((ext_vector_type(4)));

#define MF(a, b, c) __builtin_amdgcn_mfma_f32_16x16x32_f16((a), (b), (c), 0, 0, 0)

// ---- LDS map (bytes) ----
// enc h limbs (double-buffered): (p*2+limb)*HPLANE + n*272 + k*2   (n<16, k<128)
//   pitch 272 = 17 x 16B granules (odd) -> b128 frag reads are 2-way max (free)
// dec h limbs: DBASE + limb*DPLANE + n*80 + k*2                    (n<16, k<32)
#define HPLANE 4352
#define DBASE  17408
#define DPLANE 1280
#define LDS_BYTES 19968

__device__ __forceinline__ float fast_tanh(float z) {
    // identical to rounds 1-4 (verified error budget)
    float az = fabsf(z);
    float e  = __expf(-2.0f * az);
    float r  = 1.0f - 2.0f * e * __builtin_amdgcn_rcpf(1.0f + e);
    return copysignf(r, z);
}

__device__ __forceinline__ unsigned long long pack4h(_Float16 a, _Float16 b,
                                                     _Float16 c, _Float16 d) {
    union { _Float16 h[4]; unsigned long long u; } u;
    u.h[0] = a; u.h[1] = b; u.h[2] = c; u.h[3] = d;
    return u.u;
}

// One block = 16 batch rows, 256 threads (4 waves).
// Encoder: Y(128x16) = [We_hh|We_ih](128x160) . [h;x](160x16), fp16 double-limb
// (W0H0+W0H1+W1H0). Wave w owns M-tiles {2w,2w+1}; x comes from per-lane global
// register prefetch (no LDS); ONE barrier/step.
// Decoder (wave 0 only): 16 rows batched, M=K=29->32, 4 limb products,
// intra-wave LDS h round-trip, zero barriers.
__global__ __launch_bounds__(256, 1) void rnn_fused(
    const float* __restrict__ x,      // (B,S,V)
    const float* __restrict__ We_ih,  // (H,V)
    const float* __restrict__ We_hh,  // (H,H)
    const float* __restrict__ be_ih,  // (H)
    const float* __restrict__ be_hh,  // (H)
    const float* __restrict__ Wd_ih,  // (V,H)
    const float* __restrict__ Wd_hh,  // (V,V)
    const float* __restrict__ bd_ih,  // (V)
    const float* __restrict__ bd_hh,  // (V)
    float* __restrict__ out)          // (B,S,V)
{
    __shared__ f4 ldsv[LDS_BYTES / 16];
    char* lds = (char*)ldsv;

    const int tid  = threadIdx.x;
    const int w    = tid >> 6;     // wave 0..3
    const int lane = tid & 63;
    const int n    = lane & 15;    // batch row within group / A m-low
    const int q    = lane >> 4;    // quad
    const int b0   = blockIdx.x * ROWS;

    // ---- zero LDS (h_enc(0)=0, h_dec(0)=0, pad lanes stay 0) ----
    for (int o = tid; o < LDS_BYTES / 4; o += 256) ((float*)lds)[o] = 0.0f;

    // ---- encoder A fragments (weights, fp16 limbs) -> registers ----
    // A[m][k]: m = lane&15 (+16/tile), k = quad*8+j (+32/kt)   [r4-verified]
    h8 A[2][5][2];
    #pragma unroll
    for (int tt = 0; tt < 2; ++tt) {
        const int m = 32 * w + 16 * tt + n;
        #pragma unroll
        for (int kt = 0; kt < 5; ++kt) {
            #pragma unroll
            for (int j = 0; j < 8; ++j) {
                int k = 32 * kt + 8 * q + j;
                float v;
                if (k < HH) v = We_hh[m * HH + k];
                else { int c = k - HH; v = (c < VV) ? We_ih[m * VV + c] : 0.0f; }
                _Float16 l0 = (_Float16)v;
                A[tt][kt][0][j] = l0;
                A[tt][kt][1][j] = (_Float16)(v - (float)l0);
            }
        }
    }
    float bias[2][4];
    #pragma unroll
    for (int tt = 0; tt < 2; ++tt)
        #pragma unroll
        for (int r = 0; r < 4; ++r) {
            int m = 32 * w + 16 * tt + 4 * q + r;
            bias[tt][r] = be_ih[m] + be_hh[m];
        }

    // ---- x: per-lane register prefetch (batch n, cols 8q..8q+7, clamped; the
    // clamped-garbage cols >=29 multiply zero A-pad, contributing 0) ----
    const float* xrow = x + (size_t)(b0 + n) * (SS * VV);
    float xc[8];
    #pragma unroll
    for (int j = 0; j < 8; ++j) { int k = 8 * q + j; if (k > VV - 1) k = VV - 1; xc[j] = xrow[k]; }

    __syncthreads();

    int p = 0;
    for (int t = 0; t < SS; ++t) {
        // prefetch x(t+1) early (latency hidden under this step's compute)
        float xnx[8];
        {
            int tn = t + 1; if (tn >= SS) tn = SS - 1;
            const float* pr = xrow + tn * VV;
            #pragma unroll
            for (int j = 0; j < 8; ++j) { int k = 8 * q + j; if (k > VV - 1) k = VV - 1; xnx[j] = pr[k]; }
        }

        // x limbs (register-only)
        h8 bx0, bx1;
        #pragma unroll
        for (int j = 0; j < 8; ++j) {
            _Float16 l0 = (_Float16)xc[j];
            bx0[j] = l0; bx1[j] = (_Float16)(xc[j] - (float)l0);
        }

        // H B-fragments, kt order rotated per wave to spread LDS arbiter load
        const char* hb = lds + p * (2 * HPLANE) + n * 272 + q * 16;
        h8 b0v[4], b1v[4];
        #pragma unroll
        for (int c = 0; c < 4; ++c) {
            int kt = (c + w) & 3;
            b0v[kt] = *(const h8*)(hb + kt * 64);
            b1v[kt] = *(const h8*)(hb + HPLANE + kt * 64);
        }

        f4 C0[2], C1[2], C2[2];
        #pragma unroll
        for (int tt = 0; tt < 2; ++tt) {
            C0[tt] = (f4){0.f, 0.f, 0.f, 0.f};
            C1[tt] = (f4){0.f, 0.f, 0.f, 0.f};
            C2[tt] = (f4){0.f, 0.f, 0.f, 0.f};
            // x products first: no LDS dependency, runs while H frags land
            C0[tt] = MF(A[tt][4][0], bx0, C0[tt]);
            C1[tt] = MF(A[tt][4][0], bx1, C1[tt]);
            C2[tt] = MF(A[tt][4][1], bx0, C2[tt]);
        }
        #pragma unroll
        for (int c = 0; c < 4; ++c) {
            int kt = (c + w) & 3;
            #pragma unroll
            for (int tt = 0; tt < 2; ++tt) {
                C0[tt] = MF(A[tt][kt][0], b0v[kt], C0[tt]);
                C1[tt] = MF(A[tt][kt][0], b1v[kt], C1[tt]);
                C2[tt] = MF(A[tt][kt][1], b0v[kt], C2[tt]);
            }
        }

        // epilogue: sum limb products + bias, tanh, split, publish
        // C/D: col = lane&15 = n, row = quad*4 + reg = m    [r4-verified]
        char* wbase = lds + (p ^ 1) * (2 * HPLANE);
        #pragma unroll
        for (int tt = 0; tt < 2; ++tt) {
            _Float16 l0[4], l1[4];
            #pragma unroll
            for (int r = 0; r < 4; ++r) {
                float y = C0[tt][r] + C1[tt][r] + C2[tt][r] + bias[tt][r];
                float h = fast_tanh(y);
                l0[r] = (_Float16)h;
                l1[r] = (_Float16)(h - (float)l0[r]);
            }
            int off = n * 272 + 2 * (32 * w + 16 * tt + 4 * q);
            *(unsigned long long*)(wbase + off)          = pack4h(l0[0], l0[1], l0[2], l0[3]);
            *(unsigned long long*)(wbase + HPLANE + off) = pack4h(l1[0], l1[1], l1[2], l1[3]);
        }

        #pragma unroll
        for (int j = 0; j < 8; ++j) xc[j] = xnx[j];

        __syncthreads();
        p ^= 1;
    }
    // SS even -> encoded limbs in planes (p=0): lds[0..2*HPLANE)

    if (w != 0) return;

    // ================= decoder (wave 0 only, no barriers) =================
    // dec_in: D[tt] = Wd_ih . enc + bd, via MFMA on the limbs already in LDS
    f4 D[2];
    {
        h8 e0[4], e1[4];
        const char* hb = lds + n * 272 + q * 16;
        #pragma unroll
        for (int kt = 0; kt < 4; ++kt) {
            e0[kt] = *(const h8*)(hb + kt * 64);
            e1[kt] = *(const h8*)(hb + HPLANE + kt * 64);
        }
        #pragma unroll
        for (int tt = 0; tt < 2; ++tt) {
            const int row = 16 * tt + n;
            const bool vr = row < VV;
            f4 Cd = (f4){0.f, 0.f, 0.f, 0.f};
            #pragma unroll
            for (int kt = 0; kt < 4; ++kt) {
                h8 A0, A1;
                #pragma unroll
                for (int j = 0; j < 8; ++j) {
                    int k = 32 * kt + 8 * q + j;
                    float v = vr ? Wd_ih[row * HH + k] : 0.0f;
                    _Float16 l0 = (_Float16)v;
                    A0[j] = l0; A1[j] = (_Float16)(v - (float)l0);
                }
                Cd = MF(A0, e0[kt], Cd);
                Cd = MF(A0, e1[kt], Cd);
                Cd = MF(A1, e0[kt], Cd);
            }
            #pragma unroll
            for (int r = 0; r < 4; ++r) {
                int m = 16 * tt + 4 * q + r;
                Cd[r] += (m < VV) ? (bd_ih[m] + bd_hh[m]) : 0.0f;
            }
            D[tt] = Cd;
        }
    }

    // Wd_hh A fragments (rows 16tt+n, k=8q+j; zero-padded)
    h8 Ad0[2], Ad1[2];
    #pragma unroll
    for (int tt = 0; tt < 2; ++tt) {
        const int row = 16 * tt + n;
        #pragma unroll
        for (int j = 0; j < 8; ++j) {
            int k = 8 * q + j;
            float v = (row < VV && k < VV) ? Wd_hh[row * VV + k] : 0.0f;
            _Float16 l0 = (_Float16)v;
            Ad0[tt][j] = l0; Ad1[tt][j] = (_Float16)(v - (float)l0);
        }
    }

    float* outn = out + (size_t)(b0 + n) * (SS * VV);
    const char* db0 = lds + DBASE + n * 80 + q * 16;

    for (int t = 0; t < SS; ++t) {
        // read h(t) limbs (zeros at t=0 from the init fill)
        h8 B0 = *(const h8*)db0;
        h8 B1 = *(const h8*)(db0 + DPLANE);
        #pragma unroll
        for (int tt = 0; tt < 2; ++tt) {
            // full fp16-pair product: W0H0 + W1H1 | W0H1 + W1H0 (two chains of 2)
            f4 Ca = MF(Ad0[tt], B0, D[tt]);
            Ca = MF(Ad1[tt], B1, Ca);
            f4 Cb = (f4){0.f, 0.f, 0.f, 0.f};
            Cb = MF(Ad0[tt], B1, Cb);
            Cb = MF(Ad1[tt], B0, Cb);

            _Float16 l0[4], l1[4];
            float hv[4];
            #pragma unroll
            for (int r = 0; r < 4; ++r) {
                float h = fast_tanh(Ca[r] + Cb[r]);
                hv[r] = h;
                l0[r] = (_Float16)h;
                l1[r] = (_Float16)(h - (float)l0[r]);
            }
            char* wb = lds + DBASE + n * 80 + 32 * tt + 8 * q;
            *(unsigned long long*)wb            = pack4h(l0[0], l0[1], l0[2], l0[3]);
            *(unsigned long long*)(wb + DPLANE) = pack4h(l1[0], l1[1], l1[2], l1[3]);

            #pragma unroll
            for (int r = 0; r < 4; ++r) {
                int m = 16 * tt + 4 * q + r;
                if (m < VV) outn[t * VV + m] = hv[r];
            }
        }
    }
}

extern "C" void kernel_launch(void* const* d_in, const int* in_sizes, int n_in,
                              void* d_out, int out_size, void* d_ws, size_t ws_size,
                              hipStream_t stream) {
    const float* x     = (const float*)d_in[0];
    const float* We_ih = (const float*)d_in[1];
    const float* We_hh = (const float*)d_in[2];
    const float* be_ih = (const float*)d_in[3];
    const float* be_hh = (const float*)d_in[4];
    const float* Wd_ih = (const float*)d_in[5];
    const float* Wd_hh = (const float*)d_in[6];
    const float* bd_ih = (const float*)d_in[7];
    const float* bd_hh = (const float*)d_in[8];
    float* out = (float*)d_out;

    rnn_fused<<<dim3(NBLK), dim3(256), 0, stream>>>(
        x, We_ih, We_hh, be_ih, be_hh, Wd_ih, Wd_hh, bd_ih, bd_hh, out);
}

// Round 7
// 1931.088 us; speedup vs baseline: 31.2531x; 31.2531x over previous
//
#include <hip/hip_runtime.h>

#define SS 2048
#define VV 29
#define HH 128
#define ROWS 16
#define NBLK 32              // 512 rows / 16 per block
#define XSTRIDE (SS * VV)    // 59392 floats per batch row

typedef _Float16 h8 __attribute__((ext_vector_type(8)));
typedef float    f4 __attribute__((ext_vector_type(4)));

#define MF(a, b, c) __builtin_amdgcn_mfma_f32_16x16x32_f16((a), (b), (c), 0, 0, 0)

// ---------------- LDS map (bytes) ----------------
// H limb planes (double-buffered): (p*2+limb)*HPLANE + n*272 + k*2  (n<16,k<128)
//   row pitch 272B = 17 granules (odd) -> b128 frag reads 2-way max (free, m136)
// X ring: XB + half*XHALF + limb*XPLANE + n*528 + s*64 + v*2  (half<2,s<8,v<32)
//   row pitch 528B = 33 granules (odd) -> b128 reads 2-way max; pads v>=29 stay 0
#define HPLANE 4352
#define XB     17408
#define XHALF  16896
#define XPLANE 8448
#define XROWP  528
#define LDS_BYTES 51200

__device__ __forceinline__ float fast_tanh(float z) {
    // identical to rounds 1-6 (verified error budget)
    float az = fabsf(z);
    float e  = __expf(-2.0f * az);
    float r  = 1.0f - 2.0f * e * __builtin_amdgcn_rcpf(1.0f + e);
    return copysignf(r, z);
}

__device__ __forceinline__ unsigned long long pack4h(_Float16 a, _Float16 b,
                                                     _Float16 c, _Float16 d) {
    union { _Float16 h[4]; unsigned long long u; } u;
    u.h[0] = a; u.h[1] = b; u.h[2] = c; u.h[3] = d;
    return u.u;
}

// x refill helpers. Thread constants: v = tid&31, s = (tid>>5)&7, row = ii.
// R6 BUGFIX: xgp base holds ONLY row+v (xs enters solely via T*VV). The r6
// version pre-added xs*VV into xgp AND folded xs into T -> step skew + OOB
// read past the x buffer tail (block 31) -> illegal-address abort.
// With T clamped to SS-1, max offset = ii*XSTRIDE + (SS-1)*VV + xv: in-bounds.
#define XLOAD(T0)                                                             \
    if (xvalid) {                                                             \
        _Pragma("unroll")                                                     \
        for (int ii = 0; ii < 16; ++ii) {                                     \
            int T = (T0) + xs; if (T > SS - 1) T = SS - 1;                    \
            xr[ii] = xgp[(size_t)ii * XSTRIDE + T * VV];                      \
        }                                                                     \
    }

#define XSTORE(T0)                                                            \
    if (xvalid) {                                                             \
        char* bp = lds + XB + (((T0) >> 3) & 1) * XHALF + xs * 64 + xv * 2;   \
        _Pragma("unroll")                                                     \
        for (int ii = 0; ii < 16; ++ii) {                                     \
            _Float16 l0 = (_Float16)xr[ii];                                   \
            _Float16 l1 = (_Float16)(xr[ii] - (float)l0);                     \
            *(_Float16*)(bp + ii * XROWP)          = l0;                      \
            *(_Float16*)(bp + ii * XROWP + XPLANE) = l1;                      \
        }                                                                     \
    }

// Encoder: one block = 16 batch rows, 256 threads (4 waves).
// Y(128x16) = [We_hh|We_ih](128x160) . [h;x](160x16), fp16 double-limb
// (W0H0 + W0H1 + W1H0). Wave w owns M-tiles {2w,2w+1}. ONE barrier/step.
// ALL register-array indices are compile-time (r5 lesson: runtime index ->
// scratch demotion -> 40x slowdown).
__global__ __launch_bounds__(256, 1) void enc_kernel(
    const float* __restrict__ x,
    const float* __restrict__ We_ih,
    const float* __restrict__ We_hh,
    const float* __restrict__ be_ih,
    const float* __restrict__ be_hh,
    float* __restrict__ out)
{
    __shared__ f4 ldsv[LDS_BYTES / 16];
    char* lds = (char*)ldsv;

    const int tid  = threadIdx.x;
    const int w    = tid >> 6;
    const int lane = tid & 63;
    const int n    = lane & 15;
    const int q    = lane >> 4;
    const int b0   = blockIdx.x * ROWS;

    // x-refill thread constants (row offset and v only; step term added in XLOAD)
    const int  xv     = tid & 31;
    const int  xs     = (tid >> 5) & 7;
    const bool xvalid = xv < VV;
    const float* xgp  = x + (size_t)b0 * XSTRIDE + xv;

    // ---- zero LDS (h(0)=0; x pads v>=29 stay 0 forever) ----
    for (int o = tid; o < LDS_BYTES / 16; o += 256) {
        f4 z = {0.f, 0.f, 0.f, 0.f};
        ldsv[o] = z;
    }

    // ---- A fragments (weights, fp16 limbs) -> registers, compile-time indexed ----
    // A[m][k]: m = lane&15 (+16/tile), k = quad*8+j (+32/kt)  [r4-verified]
    h8 A[2][5][2];
    #pragma unroll
    for (int tt = 0; tt < 2; ++tt) {
        const int m = 32 * w + 16 * tt + n;
        #pragma unroll
        for (int kt = 0; kt < 5; ++kt) {
            #pragma unroll
            for (int j = 0; j < 8; ++j) {
                int k = 32 * kt + 8 * q + j;
                float v;
                if (k < HH) v = We_hh[m * HH + k];
                else { int c = k - HH; v = (c < VV) ? We_ih[m * VV + c] : 0.0f; }
                _Float16 l0 = (_Float16)v;
                A[tt][kt][0][j] = l0;
                A[tt][kt][1][j] = (_Float16)(v - (float)l0);
            }
        }
    }
    float bias[2][4];
    #pragma unroll
    for (int tt = 0; tt < 2; ++tt)
        #pragma unroll
        for (int r = 0; r < 4; ++r) {
            int m = 32 * w + 16 * tt + 4 * q + r;
            bias[tt][r] = be_ih[m] + be_hh[m];
        }

    __syncthreads();   // zero-fill complete before XSTORE touches shared dwords

    // ---- prime x ring: steps 0..15 in LDS, 16..23 in flight ----
    float xr[16];
    XLOAD(0);  XSTORE(0);
    XLOAD(8);  XSTORE(8);
    XLOAD(16);
    __syncthreads();

    int p = 0;
    for (int t = 0; t < SS; ++t) {
        // ---- B fragments (LDS, compile-time kt order) ----
        const char* hb = lds + p * (2 * HPLANE) + n * 272 + q * 16;
        h8 b0v[4], b1v[4];
        #pragma unroll
        for (int kt = 0; kt < 4; ++kt) {
            b0v[kt] = *(const h8*)(hb + kt * 64);
            b1v[kt] = *(const h8*)(hb + HPLANE + kt * 64);
        }
        const char* xp = lds + XB + ((t >> 3) & 1) * XHALF + n * XROWP + (t & 7) * 64 + q * 16;
        h8 bx0 = *(const h8*)xp;
        h8 bx1 = *(const h8*)(xp + XPLANE);

        f4 C0[2], C1[2], C2[2];
        #pragma unroll
        for (int tt = 0; tt < 2; ++tt) {
            C0[tt] = (f4){0.f, 0.f, 0.f, 0.f};
            C1[tt] = (f4){0.f, 0.f, 0.f, 0.f};
            C2[tt] = (f4){0.f, 0.f, 0.f, 0.f};
            C0[tt] = MF(A[tt][4][0], bx0, C0[tt]);
            C1[tt] = MF(A[tt][4][0], bx1, C1[tt]);
            C2[tt] = MF(A[tt][4][1], bx0, C2[tt]);
        }
        #pragma unroll
        for (int kt = 0; kt < 4; ++kt) {
            #pragma unroll
            for (int tt = 0; tt < 2; ++tt) {
                C0[tt] = MF(A[tt][kt][0], b0v[kt], C0[tt]);
                C1[tt] = MF(A[tt][kt][0], b1v[kt], C1[tt]);
                C2[tt] = MF(A[tt][kt][1], b0v[kt], C2[tt]);
            }
        }

        // ---- epilogue: tanh, limb-split, publish (8B packed writes) ----
        // C/D: col = lane&15 = n, row = quad*4 + reg = m   [r4-verified]
        char* wbase = lds + (p ^ 1) * (2 * HPLANE);
        #pragma unroll
        for (int tt = 0; tt < 2; ++tt) {
            _Float16 l0[4], l1[4];
            float hv[4];
            #pragma unroll
            for (int r = 0; r < 4; ++r) {
                float y = C0[tt][r] + C1[tt][r] + C2[tt][r] + bias[tt][r];
                hv[r] = fast_tanh(y);
                l0[r] = (_Float16)hv[r];
                l1[r] = (_Float16)(hv[r] - (float)l0[r]);
            }
            int off = n * 272 + 2 * (32 * w + 16 * tt + 4 * q);
            *(unsigned long long*)(wbase + off)          = pack4h(l0[0], l0[1], l0[2], l0[3]);
            *(unsigned long long*)(wbase + HPLANE + off) = pack4h(l1[0], l1[1], l1[2], l1[3]);

            if (t == SS - 1) {
                // encoded h (fp32) -> row's own out region (decoder reads it first)
                int m0 = 32 * w + 16 * tt + 4 * q;
                f4 hq = {hv[0], hv[1], hv[2], hv[3]};
                *(f4*)(out + (size_t)(b0 + n) * XSTRIDE + m0) = hq;
            }
        }

        if (t && (t & 7) == 0) { XSTORE(t + 8); XLOAD(t + 16); }

        __syncthreads();
        p ^= 1;
    }
}

// Decoder: one block per batch row, single wave, h in lanes.
// Broadcast via v_readlane (VALU pipe) -- replaces shfl/ds_bpermute which
// measured 1312 cyc/step (r4 split). Zero barriers in the loop.
__global__ __launch_bounds__(64) void dec_kernel(
    const float* __restrict__ Wd_ih,  // (V,H)
    const float* __restrict__ Wd_hh,  // (V,V)
    const float* __restrict__ bd_ih,  // (V)
    const float* __restrict__ bd_hh,  // (V)
    float* __restrict__ out)          // (B,S,V); first 128 floats/row = encoded
{
    const int row  = blockIdx.x;
    const int lane = threadIdx.x;
    float* orow = out + (size_t)row * XSTRIDE;

    __shared__ float enc[HH];
    enc[lane]      = orow[lane];
    enc[lane + 64] = orow[lane + 64];
    __syncthreads();

    const int r = (lane < VV) ? lane : (VV - 1);   // lanes >=29 mirror row 28

    float di = bd_ih[r] + bd_hh[r];
    {
        const float* wdi = Wd_ih + r * HH;
        float d0 = 0.f, d1 = 0.f, d2 = 0.f, d3 = 0.f;
        #pragma unroll
        for (int j = 0; j < HH; j += 4) {
            d0 += wdi[j + 0] * enc[j + 0];
            d1 += wdi[j + 1] * enc[j + 1];
            d2 += wdi[j + 2] * enc[j + 2];
            d3 += wdi[j + 3] * enc[j + 3];
        }
        di += (d0 + d1) + (d2 + d3);
    }

    float wd[VV];
    {
        const float* wdr = Wd_hh + r * VV;
        #pragma unroll
        for (int j = 0; j < VV; ++j) wd[j] = wdr[j];
    }

    float hd = 0.0f;
    for (int t = 0; t < SS; ++t) {
        const int hbits = __float_as_int(hd);
        float a0 = di, a1 = 0.f, a2 = 0.f, a3 = 0.f;
        #pragma unroll
        for (int j = 0; j < VV; j += 4) {
            a0 += wd[j] * __int_as_float(__builtin_amdgcn_readlane(hbits, j));
            if (j + 1 < VV) a1 += wd[j + 1] * __int_as_float(__builtin_amdgcn_readlane(hbits, j + 1));
            if (j + 2 < VV) a2 += wd[j + 2] * __int_as_float(__builtin_amdgcn_readlane(hbits, j + 2));
            if (j + 3 < VV) a3 += wd[j + 3] * __int_as_float(__builtin_amdgcn_readlane(hbits, j + 3));
        }
        float hn = fast_tanh((a0 + a1) + (a2 + a3));
        hd = hn;
        if (lane < VV) orow[t * VV + lane] = hn;
    }
}

extern "C" void kernel_launch(void* const* d_in, const int* in_sizes, int n_in,
                              void* d_out, int out_size, void* d_ws, size_t ws_size,
                              hipStream_t stream) {
    const float* x     = (const float*)d_in[0];
    const float* We_ih = (const float*)d_in[1];
    const float* We_hh = (const float*)d_in[2];
    const float* be_ih = (const float*)d_in[3];
    const float* be_hh = (const float*)d_in[4];
    const float* Wd_ih = (const float*)d_in[5];
    const float* Wd_hh = (const float*)d_in[6];
    const float* bd_ih = (const float*)d_in[7];
    const float* bd_hh = (const float*)d_in[8];
    float* out = (float*)d_out;

    enc_kernel<<<dim3(NBLK), dim3(256), 0, stream>>>(
        x, We_ih, We_hh, be_ih, be_hh, out);
    dec_kernel<<<dim3(512), dim3(64), 0, stream>>>(
        Wd_ih, Wd_hh, bd_ih, bd_hh, out);
}